// Round 18
// baseline (3670.548 us; speedup 1.0000x reference)
//
#include <hip/hip_runtime.h>

static constexpr int   BATCH = 131072;
static constexpr int   TS    = 30;
static constexpr int   DD    = 10;
static constexpr int   HH    = 20;
static constexpr float EPSV  = 1e-5f;
static constexpr float INV_B = 1.0f / (float)BATCH;

static constexpr int NBLK = 512;            // 2 blocks/CU (oversubscribed, co-resident)
static constexpr int NTHR = 256;
static constexpr int NS   = 8;              // stat slot spread (blockIdx&7)
static constexpr int GRPS = 16;             // barrier tree groups
static constexpr int GSZ  = NBLK / GRPS;    // 32 arrivals per group counter
static constexpr int NVA  = 230;            // 210 tri second-moments + 20 sums
static constexpr int NVB  = 40;             // 20 sums + 20 sumsq
static constexpr int STRA = NVA * NS;
static constexpr int STRB = NVB * NS;
static constexpr int CTRW = 288;            // uints/phase: groups @ g*16 (0..255), root @ 256
static constexpr int NPH  = 2 * TS + 1;     // 61 phase slots

__device__ __forceinline__ int tri(int k, int l) {  // k <= l
    return k * (41 - k) / 2 + (l - k);
}

template <int CTRL>
__device__ __forceinline__ float dpp_add(float v) {
    int x = __builtin_amdgcn_update_dpp(0, __float_as_int(v), CTRL, 0xF, 0xF, true);
    return v + __int_as_float(x);
}

__device__ __forceinline__ float rowsum16(float v) {
    v = dpp_add<0x111>(v);
    v = dpp_add<0x112>(v);
    v = dpp_add<0x114>(v);
    v = dpp_add<0x118>(v);
    return v;   // lane 15 of each 16 holds the total
}

__device__ __forceinline__ float aloadf(const float* p) {
    return __hip_atomic_load(p, __ATOMIC_RELAXED, __HIP_MEMORY_SCOPE_AGENT);
}

// 2-level relaxed tree barrier (R15-R17-proven protocol; widened to 16 groups).
__device__ __forceinline__ void gbar(unsigned* __restrict__ base, int tid, int grpN) {
    __syncthreads();   // drains this block's vmem (incl. stat atomics)
    if (tid == 0) {
        if (__hip_atomic_fetch_add(base + grpN * 16, 1u, __ATOMIC_RELAXED,
                                   __HIP_MEMORY_SCOPE_AGENT) == (unsigned)(GSZ - 1))
            __hip_atomic_fetch_add(base + 256, 1u, __ATOMIC_RELAXED,
                                   __HIP_MEMORY_SCOPE_AGENT);
        while (__hip_atomic_load(base + 256, __ATOMIC_RELAXED,
                                 __HIP_MEMORY_SCOPE_AGENT) < (unsigned)GRPS)
            __builtin_amdgcn_s_sleep(1);
    }
    __syncthreads();
}

// ---------------- the whole sequence in ONE regular-launch persistent kernel
__global__ void __launch_bounds__(NTHR, 2)   // force >=2 blocks/CU co-residency
rnn_all(const float* __restrict__ x, float* __restrict__ outg,
        const float* __restrict__ W1, const float* __restrict__ W2,
        const float* __restrict__ W3, const float* __restrict__ b3,
        const float* __restrict__ g0, const float* __restrict__ be0,
        const float* __restrict__ g1, const float* __restrict__ be1,
        const float* __restrict__ g2, const float* __restrict__ be2,
        float* __restrict__ redA, float* __restrict__ redB,
        unsigned* __restrict__ ctr)
{
    __shared__ float lred[16 * NVA];
    __shared__ float sM[230], sMu[20], sCov[400], sU[400], sP[400];
    __shared__ float sW1[400], sW2[400], sW3[200], sB3[10];
    __shared__ float sA0[20], sC0[20], sA1[20], sC1[20], sA2[20], sC2[20];

    const int tid     = threadIdx.x;
    const int grp     = tid >> 4;             // 0..15
    const bool lane15 = (tid & 15) == 15;
    const int slot    = blockIdx.x & (NS - 1);
    const int grpN    = blockIdx.x & (GRPS - 1);
    const int row     = blockIdx.x * NTHR + tid;   // one batch row per thread

    // prev lives in REGISTERS for the whole sequence
    float pv[DD];
#pragma unroll
    for (int d = 0; d < DD; ++d) pv[d] = 0.0f;

    float xv[DD];
    {
        const float2* px = reinterpret_cast<const float2*>(x + (size_t)row * TS * DD);
#pragma unroll
        for (int i = 0; i < 5; ++i) { float2 v = px[i]; xv[2 * i] = v.x; xv[2 * i + 1] = v.y; }
    }

    // ---- statsA(0): prev==0
#define H0(i) ((i) < DD ? xv[i] : 0.0f)
    {
        int v = 0;
#pragma unroll
        for (int k = 0; k < 2 * DD; ++k) {
#pragma unroll
            for (int l = k; l < 2 * DD; ++l) {
                float r = rowsum16(H0(k) * H0(l));
                if (lane15) lred[grp * NVA + v] = r;
                ++v;
            }
        }
#pragma unroll
        for (int k = 0; k < 2 * DD; ++k) {
            float r = rowsum16(H0(k));
            if (lane15) lred[grp * NVA + 210 + k] = r;
        }
    }
#undef H0
    __syncthreads();
    if (tid < NVA) {
        float acc = 0.0f;
#pragma unroll
        for (int g = 0; g < 16; ++g) acc += lred[g * NVA + tid];
        atomicAdd(redA + tid * NS + slot, acc);
    }
    gbar(ctr + (size_t)(2 * TS) * CTRW, tid, grpN);   // init barrier (slot 60)

    for (int t = 0; t < TS; ++t) {
        // ---- stage weights for this step
        for (int i = tid; i < 400; i += NTHR) { sW1[i] = W1[t * 400 + i]; sW2[i] = W2[t * 400 + i]; }
        if (tid < 200) sW3[tid] = W3[t * 200 + tid];
        if (tid >= 200 && tid < 210) sB3[tid - 200] = b3[t * DD + (tid - 200)];

        // ---- prefetch x(t+1)
        float xn[DD];
        if (t + 1 < TS) {
            const float2* px = reinterpret_cast<const float2*>(x + (size_t)row * TS * DD + (t + 1) * DD);
#pragma unroll
            for (int i = 0; i < 5; ++i) { float2 v = px[i]; xn[2 * i] = v.x; xn[2 * i + 1] = v.y; }
        }

        // ---- readback statsA[t] (relaxed agent atomic loads)
        if (tid < NVA) {
            const float* p = redA + (size_t)t * STRA + tid * NS;
            float s = 0.0f;
#pragma unroll
            for (int i = 0; i < NS; ++i) s += aloadf(p + i);
            sM[tid] = s;
        }
        __syncthreads();

        // ---- BN0 params
        if (tid < 20) {
            float mu  = sM[210 + tid] * INV_B;
            float var = fmaf(-mu, mu, sM[tri(tid, tid)] * INV_B);
            float a   = g0[t * 20 + tid] * rsqrtf(var + EPSV);
            sA0[tid] = a;
            sC0[tid] = fmaf(-mu, a, be0[t * 20 + tid]);
            sMu[tid] = mu;
        }
        __syncthreads();

        // ---- covariance + U = W1 ∘ A0
        for (int i = tid; i < 400; i += NTHR) {
            int k = i / 20, l = i % 20;
            int a = k < l ? k : l, b = k < l ? l : k;
            sCov[i] = fmaf(-sMu[k], sMu[l], sM[tri(a, b)] * INV_B);
            sU[i]   = sW1[i] * sA0[l];
        }
        __syncthreads();

        // ---- P[j,k] = U[j,k] * (Cov[k,:] · U[j,:])
        for (int i = tid; i < 400; i += NTHR) {
            int j = i / 20, k = i % 20;
            float acc = 0.0f;
#pragma unroll
            for (int l = 0; l < 20; ++l)
                acc = fmaf(sCov[k * 20 + l], sU[j * 20 + l], acc);
            sP[i] = acc * sU[i];
        }
        __syncthreads();

        // ---- analytic BN1 params (b1 cancels in BN)
        if (tid < 20) {
            float var1 = 0.0f, m1 = 0.0f;
#pragma unroll
            for (int k = 0; k < 20; ++k) {
                var1 += sP[tid * 20 + k];
                m1    = fmaf(sU[tid * 20 + k], sMu[k], m1);
                m1    = fmaf(sW1[tid * 20 + k], sC0[k], m1);
            }
            float a1 = g1[t * 20 + tid] * rsqrtf(var1 + EPSV);
            sA1[tid] = a1;
            sC1[tid] = fmaf(-m1, a1, be1[t * 20 + tid]);
        }
        __syncthreads();

        // ---- forward layers 1,2 (y2 stays in registers)
        float y2[HH];
        {
            float hn[20];
#pragma unroll
            for (int k = 0; k < 10; ++k) hn[k]      = fmaf(xv[k], sA0[k],      sC0[k]);
#pragma unroll
            for (int k = 0; k < 10; ++k) hn[10 + k] = fmaf(pv[k], sA0[10 + k], sC0[10 + k]);

            float h1[20];
#pragma unroll
            for (int j = 0; j < 20; ++j) {
                float y = 0.0f;
#pragma unroll
                for (int k = 0; k < 20; ++k) y = fmaf(sW1[j * 20 + k], hn[k], y);
                h1[j] = fmaxf(fmaf(y, sA1[j], sC1[j]), 0.0f);
            }
#pragma unroll
            for (int j = 0; j < 20; ++j) {
                float y = 0.0f;
#pragma unroll
                for (int k = 0; k < 20; ++k) y = fmaf(sW2[j * 20 + k], h1[k], y);
                y2[j] = y;   // b2 cancels in BN2
            }
        }

        // ---- statsB
#pragma unroll
        for (int j = 0; j < 20; ++j) {
            float r = rowsum16(y2[j]);
            if (lane15) lred[grp * NVA + j] = r;
        }
#pragma unroll
        for (int j = 0; j < 20; ++j) {
            float r = rowsum16(y2[j] * y2[j]);
            if (lane15) lred[grp * NVA + 20 + j] = r;
        }
        __syncthreads();
        if (tid < NVB) {
            float acc = 0.0f;
#pragma unroll
            for (int g = 0; g < 16; ++g) acc += lred[g * NVA + tid];
            atomicAdd(redB + (size_t)t * STRB + tid * NS + slot, acc);
        }

        // ================= barrier 1 (statsB ready) =================
        gbar(ctr + (size_t)(2 * t) * CTRW, tid, grpN);

        // ---- BN2 params (relaxed agent atomic readback)
        if (tid < NVB) {
            const float* p = redB + (size_t)t * STRB + tid * NS;
            float s = 0.0f;
#pragma unroll
            for (int i = 0; i < NS; ++i) s += aloadf(p + i);
            sM[tid] = s;
        }
        __syncthreads();
        if (tid < 20) {
            float m   = sM[tid] * INV_B;
            float var = fmaf(-m, m, sM[20 + tid] * INV_B);
            float a   = g2[t * 20 + tid] * rsqrtf(var + EPSV);
            sA2[tid] = a;
            sC2[tid] = fmaf(-m, a, be2[t * 20 + tid]);
        }
        __syncthreads();

        // ---- layer 3 + output + prev (registers)
        float ov[DD];
        {
            float h2[20];
#pragma unroll
            for (int j = 0; j < 20; ++j)
                h2[j] = fmaxf(fmaf(y2[j], sA2[j], sC2[j]), 0.0f);
#pragma unroll
            for (int d = 0; d < DD; ++d) {
                float a = sB3[d];
#pragma unroll
                for (int j = 0; j < 20; ++j)
                    a = fmaf(sW3[d * 20 + j], h2[j], a);
                ov[d] = a;
            }
            float2* po = reinterpret_cast<float2*>(outg + (size_t)row * TS * DD + t * DD);
#pragma unroll
            for (int i = 0; i < 5; ++i) po[i] = make_float2(ov[2 * i], ov[2 * i + 1]);
#pragma unroll
            for (int d = 0; d < DD; ++d) pv[d] = ov[d];
        }

        // ---- statsA(t+1) + barrier 2
        if (t + 1 < TS) {
#define H0(i) ((i) < DD ? xn[i] : ov[(i) - DD])
            {
                int v = 0;
#pragma unroll
                for (int k = 0; k < 2 * DD; ++k) {
#pragma unroll
                    for (int l = k; l < 2 * DD; ++l) {
                        float r = rowsum16(H0(k) * H0(l));
                        if (lane15) lred[grp * NVA + v] = r;
                        ++v;
                    }
                }
#pragma unroll
                for (int k = 0; k < 2 * DD; ++k) {
                    float r = rowsum16(H0(k));
                    if (lane15) lred[grp * NVA + 210 + k] = r;
                }
            }
#undef H0
            __syncthreads();
            if (tid < NVA) {
                float acc = 0.0f;
#pragma unroll
                for (int g = 0; g < 16; ++g) acc += lred[g * NVA + tid];
                atomicAdd(redA + (size_t)(t + 1) * STRA + tid * NS + slot, acc);
            }
            gbar(ctr + (size_t)(2 * t + 1) * CTRW, tid, grpN);

#pragma unroll
            for (int d = 0; d < DD; ++d) xv[d] = xn[d];
        }
    }
}

extern "C" void kernel_launch(void* const* d_in, const int* in_sizes, int n_in,
                              void* d_out, int out_size, void* d_ws, size_t ws_size,
                              hipStream_t stream) {
    const float* x   = (const float*)d_in[0];
    const float* g0  = (const float*)d_in[1];
    const float* be0 = (const float*)d_in[2];
    const float* W1  = (const float*)d_in[3];
    const float* b1  = (const float*)d_in[4];   (void)b1;  // cancels in BN1
    const float* g1  = (const float*)d_in[5];
    const float* be1 = (const float*)d_in[6];
    const float* W2  = (const float*)d_in[7];
    const float* b2  = (const float*)d_in[8];   (void)b2;  // cancels in BN2
    const float* g2  = (const float*)d_in[9];
    const float* be2 = (const float*)d_in[10];
    const float* W3  = (const float*)d_in[11];
    const float* b3  = (const float*)d_in[12];
    float* out = (float*)d_out;

    const size_t redA_f = (size_t)TS * STRA;    // 55200
    const size_t redB_f = (size_t)TS * STRB;    //  9600
    const size_t ctr_u  = (size_t)NPH * CTRW;   // 17568
    float*    redA  = (float*)d_ws;
    float*    redB  = redA + redA_f;
    unsigned* ctr   = (unsigned*)(redB + redB_f);

    // zero stat accumulators + barrier counters each replay
    hipMemsetAsync(d_ws, 0, (redA_f + redB_f) * 4 + ctr_u * 4, stream);

    rnn_all<<<NBLK, NTHR, 0, stream>>>(x, out, W1, W2, W3, b3,
                                       g0, be0, g1, be1, g2, be2,
                                       redA, redB, ctr);
}

// Round 19
// 2554.748 us; speedup vs baseline: 1.4368x; 1.4368x over previous
//
#include <hip/hip_runtime.h>

static constexpr int   BATCH = 131072;
static constexpr int   TS    = 30;
static constexpr int   DD    = 10;
static constexpr int   HH    = 20;
static constexpr float EPSV  = 1e-5f;
static constexpr float INV_B = 1.0f / (float)BATCH;

static constexpr int NBLK = 256;            // == CU count; the ONLY clean spin-barrier shape
static constexpr int NTHR = 256;            // (>4 waves/CU triggers the 5GB traffic anomaly)
static constexpr int RPT  = 2;
static constexpr int TT   = NBLK * NTHR;    // 65536: rows gt and gt+TT
static constexpr int NS   = 8;              // stat slot spread (blockIdx&7)
static constexpr int GRPS = 16;             // balanced tree: 16 groups x 16 arrivals
static constexpr int GSZ  = NBLK / GRPS;
static constexpr int NVA  = 230;            // 210 tri second-moments + 20 sums
static constexpr int NVB  = 40;
static constexpr int STRA = NVA * NS;
static constexpr int STRB = NVB * NS;
static constexpr int CTRW = 272;            // groups @ g*16 (0..255), root @ 256
static constexpr int NPH  = 2 * TS + 1;

__device__ __forceinline__ int tri(int k, int l) {  // k <= l, over 20
    return k * (41 - k) / 2 + (l - k);
}

template <int CTRL>
__device__ __forceinline__ float dpp_add(float v) {
    int x = __builtin_amdgcn_update_dpp(0, __float_as_int(v), CTRL, 0xF, 0xF, true);
    return v + __int_as_float(x);
}

__device__ __forceinline__ float rowsum16(float v) {
    v = dpp_add<0x111>(v);
    v = dpp_add<0x112>(v);
    v = dpp_add<0x114>(v);
    v = dpp_add<0x118>(v);
    return v;   // lane 15 of each 16 holds the total
}

__device__ __forceinline__ float aloadf(const float* p) {
    return __hip_atomic_load(p, __ATOMIC_RELAXED, __HIP_MEMORY_SCOPE_AGENT);
}

// Balanced 2-level relaxed tree barrier (protocol proven R15-R18).
__device__ __forceinline__ void gbar(unsigned* __restrict__ base, int tid, int grpN) {
    __syncthreads();   // drains this block's vmem (incl. stat atomics)
    if (tid == 0) {
        if (__hip_atomic_fetch_add(base + grpN * 16, 1u, __ATOMIC_RELAXED,
                                   __HIP_MEMORY_SCOPE_AGENT) == (unsigned)(GSZ - 1))
            __hip_atomic_fetch_add(base + 256, 1u, __ATOMIC_RELAXED,
                                   __HIP_MEMORY_SCOPE_AGENT);
        while (__hip_atomic_load(base + 256, __ATOMIC_RELAXED,
                                 __HIP_MEMORY_SCOPE_AGENT) < (unsigned)GRPS)
            __builtin_amdgcn_s_sleep(1);
    }
    __syncthreads();
}

// ---------------- the whole sequence in ONE regular-launch persistent kernel
__global__ void __launch_bounds__(NTHR)
rnn_all(const float* __restrict__ x, float* __restrict__ outg,
        const float* __restrict__ W1, const float* __restrict__ W2,
        const float* __restrict__ W3, const float* __restrict__ b3,
        const float* __restrict__ g0, const float* __restrict__ be0,
        const float* __restrict__ g1, const float* __restrict__ be1,
        const float* __restrict__ g2, const float* __restrict__ be2,
        float* __restrict__ redA, float* __restrict__ redB,
        unsigned* __restrict__ ctr)
{
    __shared__ float lred[16 * NVA];
    __shared__ float sM[230], sMu[20], sCov[400], sU[400], sP[400];
    __shared__ float sW1[400], sW2[400], sW3[200], sB3[10];
    __shared__ float sA0[20], sC0[20], sA1[20], sC1[20], sA2[20], sC2[20];

    const int tid     = threadIdx.x;
    const int grp     = tid >> 4;
    const bool lane15 = (tid & 15) == 15;
    const int slot    = blockIdx.x & (NS - 1);
    const int grpN    = blockIdx.x & (GRPS - 1);
    const int gt      = blockIdx.x * NTHR + tid;

    float pv[RPT][DD];
#pragma unroll
    for (int r = 0; r < RPT; ++r)
#pragma unroll
        for (int d = 0; d < DD; ++d) pv[r][d] = 0.0f;

    float xv[RPT][DD];
#pragma unroll
    for (int r = 0; r < RPT; ++r) {
        const float2* px = reinterpret_cast<const float2*>(x + (size_t)(gt + r * TT) * TS * DD);
#pragma unroll
        for (int i = 0; i < 5; ++i) { float2 v = px[i]; xv[r][2 * i] = v.x; xv[r][2 * i + 1] = v.y; }
    }

    // ---- statsA(0): prev==0, full 230 (prev-moments are exact zeros)
#define H0A(i) ((i) < DD ? xv[0][i] : 0.0f)
#define H0B(i) ((i) < DD ? xv[1][i] : 0.0f)
    {
        int v = 0;
#pragma unroll
        for (int k = 0; k < 2 * DD; ++k) {
#pragma unroll
            for (int l = k; l < 2 * DD; ++l) {
                float p = fmaf(H0A(k), H0A(l), H0B(k) * H0B(l));
                float r = rowsum16(p);
                if (lane15) lred[grp * NVA + v] = r;
                ++v;
            }
        }
#pragma unroll
        for (int k = 0; k < 2 * DD; ++k) {
            float r = rowsum16(H0A(k) + H0B(k));
            if (lane15) lred[grp * NVA + 210 + k] = r;
        }
    }
#undef H0A
#undef H0B
    __syncthreads();
    if (tid < NVA) {
        float acc = 0.0f;
#pragma unroll
        for (int g = 0; g < 16; ++g) acc += lred[g * NVA + tid];
        atomicAdd(redA + tid * NS + slot, acc);
    }
    gbar(ctr + (size_t)(2 * TS) * CTRW, tid, grpN);   // init barrier

    for (int t = 0; t < TS; ++t) {
        // ---- stage weights; prefetch x(t+1)
        for (int i = tid; i < 400; i += NTHR) { sW1[i] = W1[t * 400 + i]; sW2[i] = W2[t * 400 + i]; }
        if (tid < 200) sW3[tid] = W3[t * 200 + tid];
        if (tid >= 200 && tid < 210) sB3[tid - 200] = b3[t * DD + (tid - 200)];

        float xn[RPT][DD];
        if (t + 1 < TS) {
#pragma unroll
            for (int r = 0; r < RPT; ++r) {
                const float2* px = reinterpret_cast<const float2*>(x + (size_t)(gt + r * TT) * TS * DD + (t + 1) * DD);
#pragma unroll
                for (int i = 0; i < 5; ++i) { float2 v = px[i]; xn[r][2 * i] = v.x; xn[r][2 * i + 1] = v.y; }
            }
        }

        // ---- readback statsA[t]
        if (tid < NVA) {
            const float* p = redA + (size_t)t * STRA + tid * NS;
            float s = 0.0f;
#pragma unroll
            for (int i = 0; i < NS; ++i) s += aloadf(p + i);
            sM[tid] = s;
        }
        __syncthreads();

        // ---- BN0 params
        if (tid < 20) {
            float mu  = sM[210 + tid] * INV_B;
            float var = fmaf(-mu, mu, sM[tri(tid, tid)] * INV_B);
            float a   = g0[t * 20 + tid] * rsqrtf(var + EPSV);
            sA0[tid] = a;
            sC0[tid] = fmaf(-mu, a, be0[t * 20 + tid]);
            sMu[tid] = mu;
        }
        __syncthreads();

        // ---- covariance + U = W1 ∘ A0
        for (int i = tid; i < 400; i += NTHR) {
            int k = i / 20, l = i % 20;
            int a = k < l ? k : l, b = k < l ? l : k;
            sCov[i] = fmaf(-sMu[k], sMu[l], sM[tri(a, b)] * INV_B);
            sU[i]   = sW1[i] * sA0[l];
        }
        __syncthreads();

        // ---- P[j,k] = U[j,k] * (Cov[k,:] · U[j,:])
        for (int i = tid; i < 400; i += NTHR) {
            int j = i / 20, k = i % 20;
            float acc = 0.0f;
#pragma unroll
            for (int l = 0; l < 20; ++l)
                acc = fmaf(sCov[k * 20 + l], sU[j * 20 + l], acc);
            sP[i] = acc * sU[i];
        }
        __syncthreads();

        // ---- analytic BN1 params
        if (tid < 20) {
            float var1 = 0.0f, m1 = 0.0f;
#pragma unroll
            for (int k = 0; k < 20; ++k) {
                var1 += sP[tid * 20 + k];
                m1    = fmaf(sU[tid * 20 + k], sMu[k], m1);
                m1    = fmaf(sW1[tid * 20 + k], sC0[k], m1);
            }
            float a1 = g1[t * 20 + tid] * rsqrtf(var1 + EPSV);
            sA1[tid] = a1;
            sC1[tid] = fmaf(-m1, a1, be1[t * 20 + tid]);
        }
        __syncthreads();

        // ---- forward layers 1,2
        float y2[RPT][HH];
#pragma unroll
        for (int r = 0; r < RPT; ++r) {
            float hn[20];
#pragma unroll
            for (int k = 0; k < 10; ++k) hn[k]      = fmaf(xv[r][k], sA0[k],      sC0[k]);
#pragma unroll
            for (int k = 0; k < 10; ++k) hn[10 + k] = fmaf(pv[r][k], sA0[10 + k], sC0[10 + k]);
            float h1[20];
#pragma unroll
            for (int j = 0; j < 20; ++j) {
                float y = 0.0f;
#pragma unroll
                for (int k = 0; k < 20; ++k) y = fmaf(sW1[j * 20 + k], hn[k], y);
                h1[j] = fmaxf(fmaf(y, sA1[j], sC1[j]), 0.0f);
            }
#pragma unroll
            for (int j = 0; j < 20; ++j) {
                float y = 0.0f;
#pragma unroll
                for (int k = 0; k < 20; ++k) y = fmaf(sW2[j * 20 + k], h1[k], y);
                y2[r][j] = y;
            }
        }

        // ---- EARLY statsA(t+1) x-part: 55 x⊗x moments + 10 x-sums (xn only)
        if (t + 1 < TS) {
            int c = 0;
#pragma unroll
            for (int k = 0; k < DD; ++k) {
#pragma unroll
                for (int l = k; l < DD; ++l) {
                    float p = fmaf(xn[0][k], xn[0][l], xn[1][k] * xn[1][l]);
                    float r = rowsum16(p);
                    if (lane15) lred[grp * NVA + c] = r;
                    ++c;
                }
            }
#pragma unroll
            for (int k = 0; k < DD; ++k) {
                float r = rowsum16(xn[0][k] + xn[1][k]);
                if (lane15) lred[grp * NVA + 55 + k] = r;
            }
            __syncthreads();
            if (tid < 65) {
                float acc = 0.0f;
#pragma unroll
                for (int g = 0; g < 16; ++g) acc += lred[g * NVA + tid];
                int v;
                if (tid < 55) {
                    int c2 = tid, k = 0;
                    while (c2 >= DD - k) { c2 -= DD - k; ++k; }
                    v = tri(k, k + c2);
                } else {
                    v = 210 + (tid - 55);
                }
                atomicAdd(redA + (size_t)(t + 1) * STRA + v * NS + slot, acc);
            }
            __syncthreads();
        }

        // ---- statsB
#pragma unroll
        for (int j = 0; j < 20; ++j) {
            float r = rowsum16(y2[0][j] + y2[1][j]);
            if (lane15) lred[grp * NVA + j] = r;
        }
#pragma unroll
        for (int j = 0; j < 20; ++j) {
            float r = rowsum16(fmaf(y2[0][j], y2[0][j], y2[1][j] * y2[1][j]));
            if (lane15) lred[grp * NVA + 20 + j] = r;
        }
        __syncthreads();
        if (tid < NVB) {
            float acc = 0.0f;
#pragma unroll
            for (int g = 0; g < 16; ++g) acc += lred[g * NVA + tid];
            atomicAdd(redB + (size_t)t * STRB + tid * NS + slot, acc);
        }

        // ================= barrier 1 (statsB ready) =================
        gbar(ctr + (size_t)(2 * t) * CTRW, tid, grpN);

        // ---- BN2 params
        if (tid < NVB) {
            const float* p = redB + (size_t)t * STRB + tid * NS;
            float s = 0.0f;
#pragma unroll
            for (int i = 0; i < NS; ++i) s += aloadf(p + i);
            sM[tid] = s;
        }
        __syncthreads();
        if (tid < 20) {
            float m   = sM[tid] * INV_B;
            float var = fmaf(-m, m, sM[20 + tid] * INV_B);
            float a   = g2[t * 20 + tid] * rsqrtf(var + EPSV);
            sA2[tid] = a;
            sC2[tid] = fmaf(-m, a, be2[t * 20 + tid]);
        }
        __syncthreads();

        // ---- layer 3 + output + prev
        float ov[RPT][DD];
#pragma unroll
        for (int r = 0; r < RPT; ++r) {
            float h2[20];
#pragma unroll
            for (int j = 0; j < 20; ++j)
                h2[j] = fmaxf(fmaf(y2[r][j], sA2[j], sC2[j]), 0.0f);
#pragma unroll
            for (int d = 0; d < DD; ++d) {
                float a = sB3[d];
#pragma unroll
                for (int j = 0; j < 20; ++j)
                    a = fmaf(sW3[d * 20 + j], h2[j], a);
                ov[r][d] = a;
            }
            float2* po = reinterpret_cast<float2*>(outg + (size_t)(gt + r * TT) * TS * DD + t * DD);
#pragma unroll
            for (int i = 0; i < 5; ++i) po[i] = make_float2(ov[r][2 * i], ov[r][2 * i + 1]);
#pragma unroll
            for (int d = 0; d < DD; ++d) pv[r][d] = ov[r][d];
        }

        // ---- LATE statsA(t+1): 100 x⊗prev + 55 prev⊗prev + 10 prev sums
        if (t + 1 < TS) {
            {
                int c = 0;
#pragma unroll
                for (int k = 0; k < DD; ++k) {       // x⊗prev
#pragma unroll
                    for (int l = 0; l < DD; ++l) {
                        float p = fmaf(xn[0][k], ov[0][l], xn[1][k] * ov[1][l]);
                        float r = rowsum16(p);
                        if (lane15) lred[grp * NVA + c] = r;
                        ++c;
                    }
                }
#pragma unroll
                for (int a = 0; a < DD; ++a) {       // prev⊗prev
#pragma unroll
                    for (int b = a; b < DD; ++b) {
                        float p = fmaf(ov[0][a], ov[0][b], ov[1][a] * ov[1][b]);
                        float r = rowsum16(p);
                        if (lane15) lred[grp * NVA + c] = r;
                        ++c;
                    }
                }
#pragma unroll
                for (int d = 0; d < DD; ++d) {       // prev sums
                    float r = rowsum16(ov[0][d] + ov[1][d]);
                    if (lane15) lred[grp * NVA + 155 + d] = r;
                }
            }
            __syncthreads();
            if (tid < 165) {
                float acc = 0.0f;
#pragma unroll
                for (int g = 0; g < 16; ++g) acc += lred[g * NVA + tid];
                int v;
                if (tid < 100) {
                    v = tri(tid / 10, 10 + tid % 10);
                } else if (tid < 155) {
                    int c2 = tid - 100, a = 0;
                    while (c2 >= DD - a) { c2 -= DD - a; ++a; }
                    v = tri(10 + a, 10 + a + c2);
                } else {
                    v = 220 + (tid - 155);
                }
                atomicAdd(redA + (size_t)(t + 1) * STRA + v * NS + slot, acc);
            }
            gbar(ctr + (size_t)(2 * t + 1) * CTRW, tid, grpN);

#pragma unroll
            for (int r = 0; r < RPT; ++r)
#pragma unroll
                for (int d = 0; d < DD; ++d) xv[r][d] = xn[r][d];
        }
    }
}

extern "C" void kernel_launch(void* const* d_in, const int* in_sizes, int n_in,
                              void* d_out, int out_size, void* d_ws, size_t ws_size,
                              hipStream_t stream) {
    const float* x   = (const float*)d_in[0];
    const float* g0  = (const float*)d_in[1];
    const float* be0 = (const float*)d_in[2];
    const float* W1  = (const float*)d_in[3];
    const float* b1  = (const float*)d_in[4];   (void)b1;  // cancels in BN1
    const float* g1  = (const float*)d_in[5];
    const float* be1 = (const float*)d_in[6];
    const float* W2  = (const float*)d_in[7];
    const float* b2  = (const float*)d_in[8];   (void)b2;  // cancels in BN2
    const float* g2  = (const float*)d_in[9];
    const float* be2 = (const float*)d_in[10];
    const float* W3  = (const float*)d_in[11];
    const float* b3  = (const float*)d_in[12];
    float* out = (float*)d_out;

    const size_t redA_f = (size_t)TS * STRA;
    const size_t redB_f = (size_t)TS * STRB;
    const size_t ctr_u  = (size_t)NPH * CTRW;
    float*    redA  = (float*)d_ws;
    float*    redB  = redA + redA_f;
    unsigned* ctr   = (unsigned*)(redB + redB_f);

    hipMemsetAsync(d_ws, 0, (redA_f + redB_f) * 4 + ctr_u * 4, stream);

    rnn_all<<<NBLK, NTHR, 0, stream>>>(x, out, W1, W2, W3, b3,
                                       g0, be0, g1, be1, g2, be2,
                                       redA, redB, ctr);
}

// Round 20
// 1333.665 us; speedup vs baseline: 2.7522x; 1.9156x over previous
//
#include <hip/hip_runtime.h>

static constexpr int   BATCH = 131072;
static constexpr int   TS    = 30;
static constexpr int   DD    = 10;
static constexpr int   HH    = 20;
static constexpr float EPSV  = 1e-5f;
static constexpr float INV_B = 1.0f / (float)BATCH;

static constexpr int NBLK = 256;            // == CU count; regular launch
static constexpr int NTHR = 256;            // VGPR budget 256/thread — R17 fits exactly, no spill
static constexpr int RPT  = 2;
static constexpr int TT   = NBLK * NTHR;    // 65536: rows gt and gt+TT
static constexpr int NS   = 8;              // stat slot spread (blockIdx&7)
static constexpr int GRPS = 16;             // balanced tree: 16 groups x 16 arrivals
static constexpr int GSZ  = NBLK / GRPS;
static constexpr int NVA  = 230;            // 210 tri second-moments + 20 sums
static constexpr int NVB  = 40;             // 20 sums + 20 sumsq
static constexpr int STRA = NVA * NS;
static constexpr int STRB = NVB * NS;
static constexpr int CTRW = 272;            // groups @ g*16 (0..255), root @ 256
static constexpr int NPH  = 2 * TS + 1;     // 61 phase slots

__device__ __forceinline__ int tri(int k, int l) {  // k <= l
    return k * (41 - k) / 2 + (l - k);
}

template <int CTRL>
__device__ __forceinline__ float dpp_add(float v) {
    int x = __builtin_amdgcn_update_dpp(0, __float_as_int(v), CTRL, 0xF, 0xF, true);
    return v + __int_as_float(x);
}

__device__ __forceinline__ float rowsum16(float v) {
    v = dpp_add<0x111>(v);
    v = dpp_add<0x112>(v);
    v = dpp_add<0x114>(v);
    v = dpp_add<0x118>(v);
    return v;   // lane 15 of each 16 holds the total
}

__device__ __forceinline__ float aloadf(const float* p) {
    return __hip_atomic_load(p, __ATOMIC_RELAXED, __HIP_MEMORY_SCOPE_AGENT);
}

// Balanced 2-level relaxed tree barrier (16x16; protocol proven R15-R19).
__device__ __forceinline__ void gbar(unsigned* __restrict__ base, int tid, int grpN) {
    __syncthreads();   // drains this block's vmem (incl. stat atomics)
    if (tid == 0) {
        if (__hip_atomic_fetch_add(base + grpN * 16, 1u, __ATOMIC_RELAXED,
                                   __HIP_MEMORY_SCOPE_AGENT) == (unsigned)(GSZ - 1))
            __hip_atomic_fetch_add(base + 256, 1u, __ATOMIC_RELAXED,
                                   __HIP_MEMORY_SCOPE_AGENT);
        while (__hip_atomic_load(base + 256, __ATOMIC_RELAXED,
                                 __HIP_MEMORY_SCOPE_AGENT) < (unsigned)GRPS)
            __builtin_amdgcn_s_sleep(1);
    }
    __syncthreads();
}

// ---------------- the whole sequence in ONE regular-launch persistent kernel
__global__ void __launch_bounds__(NTHR)
rnn_all(const float* __restrict__ x, float* __restrict__ outg,
        const float* __restrict__ W1, const float* __restrict__ W2,
        const float* __restrict__ W3, const float* __restrict__ b3,
        const float* __restrict__ g0, const float* __restrict__ be0,
        const float* __restrict__ g1, const float* __restrict__ be1,
        const float* __restrict__ g2, const float* __restrict__ be2,
        float* __restrict__ redA, float* __restrict__ redB,
        unsigned* __restrict__ ctr)
{
    __shared__ float lred[16 * NVA];
    __shared__ float sM[230], sMu[20], sCov[400], sU[400], sP[400];
    __shared__ float sW1[400], sW2[400], sW3[200], sB3[10];
    __shared__ float sA0[20], sC0[20], sA1[20], sC1[20], sA2[20], sC2[20];

    const int tid     = threadIdx.x;
    const int grp     = tid >> 4;
    const bool lane15 = (tid & 15) == 15;
    const int slot    = blockIdx.x & (NS - 1);
    const int grpN    = blockIdx.x & (GRPS - 1);
    const int gt      = blockIdx.x * NTHR + tid;

    // prev lives in REGISTERS for the whole sequence
    float pv[RPT][DD];
#pragma unroll
    for (int r = 0; r < RPT; ++r)
#pragma unroll
        for (int d = 0; d < DD; ++d) pv[r][d] = 0.0f;

    float xv[RPT][DD];
#pragma unroll
    for (int r = 0; r < RPT; ++r) {
        const float2* px = reinterpret_cast<const float2*>(x + (size_t)(gt + r * TT) * TS * DD);
#pragma unroll
        for (int i = 0; i < 5; ++i) { float2 v = px[i]; xv[r][2 * i] = v.x; xv[r][2 * i + 1] = v.y; }
    }

    // ---- statsA(0): prev==0, so only x-moments are nonzero
#define H0A(i) ((i) < DD ? xv[0][i] : 0.0f)
#define H0B(i) ((i) < DD ? xv[1][i] : 0.0f)
    {
        int v = 0;
#pragma unroll
        for (int k = 0; k < 2 * DD; ++k) {
#pragma unroll
            for (int l = k; l < 2 * DD; ++l) {
                float p = fmaf(H0A(k), H0A(l), H0B(k) * H0B(l));
                float r = rowsum16(p);
                if (lane15) lred[grp * NVA + v] = r;
                ++v;
            }
        }
#pragma unroll
        for (int k = 0; k < 2 * DD; ++k) {
            float r = rowsum16(H0A(k) + H0B(k));
            if (lane15) lred[grp * NVA + 210 + k] = r;
        }
    }
#undef H0A
#undef H0B
    __syncthreads();
    if (tid < NVA) {
        float acc = 0.0f;
#pragma unroll
        for (int g = 0; g < 16; ++g) acc += lred[g * NVA + tid];
        atomicAdd(redA + tid * NS + slot, acc);
    }
    gbar(ctr + (size_t)(2 * TS) * CTRW, tid, grpN);   // init barrier (slot 60)

    for (int t = 0; t < TS; ++t) {
        // ---- stage weights for this step
        for (int i = tid; i < 400; i += NTHR) { sW1[i] = W1[t * 400 + i]; sW2[i] = W2[t * 400 + i]; }
        if (tid < 200) sW3[tid] = W3[t * 200 + tid];
        if (tid >= 200 && tid < 210) sB3[tid - 200] = b3[t * DD + (tid - 200)];

        // ---- prefetch x(t+1)
        float xn[RPT][DD];
        if (t + 1 < TS) {
#pragma unroll
            for (int r = 0; r < RPT; ++r) {
                const float2* px = reinterpret_cast<const float2*>(x + (size_t)(gt + r * TT) * TS * DD + (t + 1) * DD);
#pragma unroll
                for (int i = 0; i < 5; ++i) { float2 v = px[i]; xn[r][2 * i] = v.x; xn[r][2 * i + 1] = v.y; }
            }
        }

        // ---- readback statsA[t] (relaxed agent atomic loads)
        if (tid < NVA) {
            const float* p = redA + (size_t)t * STRA + tid * NS;
            float s = 0.0f;
#pragma unroll
            for (int i = 0; i < NS; ++i) s += aloadf(p + i);
            sM[tid] = s;
        }
        __syncthreads();

        // ---- BN0 params
        if (tid < 20) {
            float mu  = sM[210 + tid] * INV_B;
            float var = fmaf(-mu, mu, sM[tri(tid, tid)] * INV_B);
            float a   = g0[t * 20 + tid] * rsqrtf(var + EPSV);
            sA0[tid] = a;
            sC0[tid] = fmaf(-mu, a, be0[t * 20 + tid]);
            sMu[tid] = mu;
        }
        __syncthreads();

        // ---- covariance + U = W1 ∘ A0
        for (int i = tid; i < 400; i += NTHR) {
            int k = i / 20, l = i % 20;
            int a = k < l ? k : l, b = k < l ? l : k;
            sCov[i] = fmaf(-sMu[k], sMu[l], sM[tri(a, b)] * INV_B);
            sU[i]   = sW1[i] * sA0[l];
        }
        __syncthreads();

        // ---- P[j,k] = U[j,k] * (Cov[k,:] · U[j,:])
        for (int i = tid; i < 400; i += NTHR) {
            int j = i / 20, k = i % 20;
            float acc = 0.0f;
#pragma unroll
            for (int l = 0; l < 20; ++l)
                acc = fmaf(sCov[k * 20 + l], sU[j * 20 + l], acc);
            sP[i] = acc * sU[i];
        }
        __syncthreads();

        // ---- analytic BN1 params (b1 cancels in BN)
        if (tid < 20) {
            float var1 = 0.0f, m1 = 0.0f;
#pragma unroll
            for (int k = 0; k < 20; ++k) {
                var1 += sP[tid * 20 + k];
                m1    = fmaf(sU[tid * 20 + k], sMu[k], m1);
                m1    = fmaf(sW1[tid * 20 + k], sC0[k], m1);
            }
            float a1 = g1[t * 20 + tid] * rsqrtf(var1 + EPSV);
            sA1[tid] = a1;
            sC1[tid] = fmaf(-m1, a1, be1[t * 20 + tid]);
        }
        __syncthreads();

        // ---- forward layers 1,2 (y2 stays in registers)
        float y2[RPT][HH];
#pragma unroll
        for (int r = 0; r < RPT; ++r) {
            float hn[20];
#pragma unroll
            for (int k = 0; k < 10; ++k) hn[k]      = fmaf(xv[r][k], sA0[k],      sC0[k]);
#pragma unroll
            for (int k = 0; k < 10; ++k) hn[10 + k] = fmaf(pv[r][k], sA0[10 + k], sC0[10 + k]);

            float h1[20];
#pragma unroll
            for (int j = 0; j < 20; ++j) {
                float y = 0.0f;
#pragma unroll
                for (int k = 0; k < 20; ++k) y = fmaf(sW1[j * 20 + k], hn[k], y);
                h1[j] = fmaxf(fmaf(y, sA1[j], sC1[j]), 0.0f);
            }
#pragma unroll
            for (int j = 0; j < 20; ++j) {
                float y = 0.0f;
#pragma unroll
                for (int k = 0; k < 20; ++k) y = fmaf(sW2[j * 20 + k], h1[k], y);
                y2[r][j] = y;   // b2 cancels in BN2
            }
        }

        // ---- statsB (combine rows, then reduce)
#pragma unroll
        for (int j = 0; j < 20; ++j) {
            float r = rowsum16(y2[0][j] + y2[1][j]);
            if (lane15) lred[grp * NVA + j] = r;
        }
#pragma unroll
        for (int j = 0; j < 20; ++j) {
            float r = rowsum16(fmaf(y2[0][j], y2[0][j], y2[1][j] * y2[1][j]));
            if (lane15) lred[grp * NVA + 20 + j] = r;
        }
        __syncthreads();
        if (tid < NVB) {
            float acc = 0.0f;
#pragma unroll
            for (int g = 0; g < 16; ++g) acc += lred[g * NVA + tid];
            atomicAdd(redB + (size_t)t * STRB + tid * NS + slot, acc);
        }

        // ================= barrier 1 (statsB ready) =================
        gbar(ctr + (size_t)(2 * t) * CTRW, tid, grpN);

        // ---- BN2 params (relaxed agent atomic readback)
        if (tid < NVB) {
            const float* p = redB + (size_t)t * STRB + tid * NS;
            float s = 0.0f;
#pragma unroll
            for (int i = 0; i < NS; ++i) s += aloadf(p + i);
            sM[tid] = s;
        }
        __syncthreads();
        if (tid < 20) {
            float m   = sM[tid] * INV_B;
            float var = fmaf(-m, m, sM[20 + tid] * INV_B);
            float a   = g2[t * 20 + tid] * rsqrtf(var + EPSV);
            sA2[tid] = a;
            sC2[tid] = fmaf(-m, a, be2[t * 20 + tid]);
        }
        __syncthreads();

        // ---- layer 3 + output + prev (registers)
        float ov[RPT][DD];
#pragma unroll
        for (int r = 0; r < RPT; ++r) {
            float h2[20];
#pragma unroll
            for (int j = 0; j < 20; ++j)
                h2[j] = fmaxf(fmaf(y2[r][j], sA2[j], sC2[j]), 0.0f);
#pragma unroll
            for (int d = 0; d < DD; ++d) {
                float a = sB3[d];
#pragma unroll
                for (int j = 0; j < 20; ++j)
                    a = fmaf(sW3[d * 20 + j], h2[j], a);
                ov[r][d] = a;
            }
            float2* po = reinterpret_cast<float2*>(outg + (size_t)(gt + r * TT) * TS * DD + t * DD);
#pragma unroll
            for (int i = 0; i < 5; ++i) po[i] = make_float2(ov[r][2 * i], ov[r][2 * i + 1]);
#pragma unroll
            for (int d = 0; d < DD; ++d) pv[r][d] = ov[r][d];
        }

        // ---- statsA(t+1) + barrier 2
        if (t + 1 < TS) {
#define H0A(i) ((i) < DD ? xn[0][i] : ov[0][(i) - DD])
#define H0B(i) ((i) < DD ? xn[1][i] : ov[1][(i) - DD])
            {
                int v = 0;
#pragma unroll
                for (int k = 0; k < 2 * DD; ++k) {
#pragma unroll
                    for (int l = k; l < 2 * DD; ++l) {
                        float p = fmaf(H0A(k), H0A(l), H0B(k) * H0B(l));
                        float r = rowsum16(p);
                        if (lane15) lred[grp * NVA + v] = r;
                        ++v;
                    }
                }
#pragma unroll
                for (int k = 0; k < 2 * DD; ++k) {
                    float r = rowsum16(H0A(k) + H0B(k));
                    if (lane15) lred[grp * NVA + 210 + k] = r;
                }
            }
#undef H0A
#undef H0B
            __syncthreads();
            if (tid < NVA) {
                float acc = 0.0f;
#pragma unroll
                for (int g = 0; g < 16; ++g) acc += lred[g * NVA + tid];
                atomicAdd(redA + (size_t)(t + 1) * STRA + tid * NS + slot, acc);
            }
            gbar(ctr + (size_t)(2 * t + 1) * CTRW, tid, grpN);

#pragma unroll
            for (int r = 0; r < RPT; ++r)
#pragma unroll
                for (int d = 0; d < DD; ++d) xv[r][d] = xn[r][d];
        }
    }
}

extern "C" void kernel_launch(void* const* d_in, const int* in_sizes, int n_in,
                              void* d_out, int out_size, void* d_ws, size_t ws_size,
                              hipStream_t stream) {
    const float* x   = (const float*)d_in[0];
    const float* g0  = (const float*)d_in[1];
    const float* be0 = (const float*)d_in[2];
    const float* W1  = (const float*)d_in[3];
    const float* b1  = (const float*)d_in[4];   (void)b1;  // cancels in BN1
    const float* g1  = (const float*)d_in[5];
    const float* be1 = (const float*)d_in[6];
    const float* W2  = (const float*)d_in[7];
    const float* b2  = (const float*)d_in[8];   (void)b2;  // cancels in BN2
    const float* g2  = (const float*)d_in[9];
    const float* be2 = (const float*)d_in[10];
    const float* W3  = (const float*)d_in[11];
    const float* b3  = (const float*)d_in[12];
    float* out = (float*)d_out;

    const size_t redA_f = (size_t)TS * STRA;    // 55200
    const size_t redB_f = (size_t)TS * STRB;    //  9600
    const size_t ctr_u  = (size_t)NPH * CTRW;   // 16592
    float*    redA  = (float*)d_ws;
    float*    redB  = redA + redA_f;
    unsigned* ctr   = (unsigned*)(redB + redB_f);

    // zero stat accumulators + barrier counters each replay
    hipMemsetAsync(d_ws, 0, (redA_f + redB_f) * 4 + ctr_u * 4, stream);

    rnn_all<<<NBLK, NTHR, 0, stream>>>(x, out, W1, W2, W3, b3,
                                       g0, be0, g1, be1, g2, be2,
                                       redA, redB, ctr);
}

// Round 21
// 1298.501 us; speedup vs baseline: 2.8268x; 1.0271x over previous
//
#include <hip/hip_runtime.h>

static constexpr int   BATCH = 131072;
static constexpr int   TS    = 30;
static constexpr int   DD    = 10;
static constexpr int   HH    = 20;
static constexpr float EPSV  = 1e-5f;
static constexpr float INV_B = 1.0f / (float)BATCH;

static constexpr int NBLK = 256;            // == CU count; regular launch
static constexpr int NTHR = 256;            // fits 256 VGPR exactly — no scratch spill
static constexpr int RPT  = 2;
static constexpr int TT   = NBLK * NTHR;    // 65536: rows gt and gt+TT
static constexpr int NS   = 8;              // stat slot spread (blockIdx&7)
static constexpr int GRPS = 8;              // R17's tree: 8 groups x 32 arrivals (best measured)
static constexpr int GSZ  = NBLK / GRPS;
static constexpr int NVA  = 230;            // 210 tri second-moments + 20 sums
static constexpr int NVB  = 40;             // 20 sums + 20 sumsq
static constexpr int STRA = NVA * NS;
static constexpr int STRB = NVB * NS;
static constexpr int CTRW = 160;            // groups @ g*16, root @ 128
static constexpr int NPH  = 2 * TS + 1;     // 61 phase slots

__device__ __forceinline__ int tri(int k, int l) {  // k <= l
    return k * (41 - k) / 2 + (l - k);
}

template <int CTRL>
__device__ __forceinline__ float dpp_add(float v) {
    int x = __builtin_amdgcn_update_dpp(0, __float_as_int(v), CTRL, 0xF, 0xF, true);
    return v + __int_as_float(x);
}

__device__ __forceinline__ float rowsum16(float v) {
    v = dpp_add<0x111>(v);
    v = dpp_add<0x112>(v);
    v = dpp_add<0x114>(v);
    v = dpp_add<0x118>(v);
    return v;   // lane 15 of each 16 holds the total
}

__device__ __forceinline__ float aloadf(const float* p) {
    return __hip_atomic_load(p, __ATOMIC_RELAXED, __HIP_MEMORY_SCOPE_AGENT);
}

// 2-level relaxed tree barrier (R15-R17-proven at regular launch).
__device__ __forceinline__ void gbar(unsigned* __restrict__ base, int tid, int grpN) {
    __syncthreads();   // drains this block's vmem (incl. stat atomics)
    if (tid == 0) {
        if (__hip_atomic_fetch_add(base + grpN * 16, 1u, __ATOMIC_RELAXED,
                                   __HIP_MEMORY_SCOPE_AGENT) == (unsigned)(GSZ - 1))
            __hip_atomic_fetch_add(base + 128, 1u, __ATOMIC_RELAXED,
                                   __HIP_MEMORY_SCOPE_AGENT);
        while (__hip_atomic_load(base + 128, __ATOMIC_RELAXED,
                                 __HIP_MEMORY_SCOPE_AGENT) < (unsigned)GRPS)
            __builtin_amdgcn_s_sleep(1);
    }
    __syncthreads();
}

// ---------------- the whole sequence in ONE regular-launch persistent kernel
__global__ void __launch_bounds__(NTHR)
rnn_all(const float* __restrict__ x, float* __restrict__ outg,
        const float* __restrict__ W1, const float* __restrict__ W2,
        const float* __restrict__ W3, const float* __restrict__ b3,
        const float* __restrict__ g0, const float* __restrict__ be0,
        const float* __restrict__ g1, const float* __restrict__ be1,
        const float* __restrict__ g2, const float* __restrict__ be2,
        float* __restrict__ redA, float* __restrict__ redB,
        unsigned* __restrict__ ctr)
{
    __shared__ float lred[16 * NVA];
    __shared__ float sM[230], sMu[20], sCov[400], sU[400], sP[400];
    __shared__ float sW1[400], sW2[400], sW3[200], sB3[10];
    __shared__ float sA0[20], sC0[20], sA1[20], sC1[20], sA2[20], sC2[20];

    const int tid     = threadIdx.x;
    const int grp     = tid >> 4;
    const bool lane15 = (tid & 15) == 15;
    const int slot    = blockIdx.x & (NS - 1);
    const int grpN    = blockIdx.x & (GRPS - 1);
    const int gt      = blockIdx.x * NTHR + tid;

    // prev lives in REGISTERS for the whole sequence
    float pv[RPT][DD];
#pragma unroll
    for (int r = 0; r < RPT; ++r)
#pragma unroll
        for (int d = 0; d < DD; ++d) pv[r][d] = 0.0f;

    float xv[RPT][DD];
#pragma unroll
    for (int r = 0; r < RPT; ++r) {
        const float2* px = reinterpret_cast<const float2*>(x + (size_t)(gt + r * TT) * TS * DD);
#pragma unroll
        for (int i = 0; i < 5; ++i) { float2 v = px[i]; xv[r][2 * i] = v.x; xv[r][2 * i + 1] = v.y; }
    }

    // ---- statsA(0): prev==0, so only x-moments are nonzero
#define H0A(i) ((i) < DD ? xv[0][i] : 0.0f)
#define H0B(i) ((i) < DD ? xv[1][i] : 0.0f)
    {
        int v = 0;
#pragma unroll
        for (int k = 0; k < 2 * DD; ++k) {
#pragma unroll
            for (int l = k; l < 2 * DD; ++l) {
                float p = fmaf(H0A(k), H0A(l), H0B(k) * H0B(l));
                float r = rowsum16(p);
                if (lane15) lred[grp * NVA + v] = r;
                ++v;
            }
        }
#pragma unroll
        for (int k = 0; k < 2 * DD; ++k) {
            float r = rowsum16(H0A(k) + H0B(k));
            if (lane15) lred[grp * NVA + 210 + k] = r;
        }
    }
#undef H0A
#undef H0B
    __syncthreads();
    if (tid < NVA) {
        float acc = 0.0f;
#pragma unroll
        for (int g = 0; g < 16; ++g) acc += lred[g * NVA + tid];
        atomicAdd(redA + tid * NS + slot, acc);
    }
    gbar(ctr + (size_t)(2 * TS) * CTRW, tid, grpN);   // init barrier (slot 60)

    for (int t = 0; t < TS; ++t) {
        // ---- stage weights for this step
        for (int i = tid; i < 400; i += NTHR) { sW1[i] = W1[t * 400 + i]; sW2[i] = W2[t * 400 + i]; }
        if (tid < 200) sW3[tid] = W3[t * 200 + tid];
        if (tid >= 200 && tid < 210) sB3[tid - 200] = b3[t * DD + (tid - 200)];

        // ---- prefetch x(t+1)
        float xn[RPT][DD];
        if (t + 1 < TS) {
#pragma unroll
            for (int r = 0; r < RPT; ++r) {
                const float2* px = reinterpret_cast<const float2*>(x + (size_t)(gt + r * TT) * TS * DD + (t + 1) * DD);
#pragma unroll
                for (int i = 0; i < 5; ++i) { float2 v = px[i]; xn[r][2 * i] = v.x; xn[r][2 * i + 1] = v.y; }
            }
        }

        // ---- readback statsA[t] (relaxed agent atomic loads)
        if (tid < NVA) {
            const float* p = redA + (size_t)t * STRA + tid * NS;
            float s = 0.0f;
#pragma unroll
            for (int i = 0; i < NS; ++i) s += aloadf(p + i);
            sM[tid] = s;
        }
        __syncthreads();

        // ---- BN0 params
        if (tid < 20) {
            float mu  = sM[210 + tid] * INV_B;
            float var = fmaf(-mu, mu, sM[tri(tid, tid)] * INV_B);
            float a   = g0[t * 20 + tid] * rsqrtf(var + EPSV);
            sA0[tid] = a;
            sC0[tid] = fmaf(-mu, a, be0[t * 20 + tid]);
            sMu[tid] = mu;
        }
        __syncthreads();

        // ---- covariance + U = W1 ∘ A0
        for (int i = tid; i < 400; i += NTHR) {
            int k = i / 20, l = i % 20;
            int a = k < l ? k : l, b = k < l ? l : k;
            sCov[i] = fmaf(-sMu[k], sMu[l], sM[tri(a, b)] * INV_B);
            sU[i]   = sW1[i] * sA0[l];
        }
        __syncthreads();

        // ---- P[j,k] = U[j,k] * (Cov[k,:] · U[j,:])
        for (int i = tid; i < 400; i += NTHR) {
            int j = i / 20, k = i % 20;
            float acc = 0.0f;
#pragma unroll
            for (int l = 0; l < 20; ++l)
                acc = fmaf(sCov[k * 20 + l], sU[j * 20 + l], acc);
            sP[i] = acc * sU[i];
        }
        __syncthreads();

        // ---- analytic BN1 params (b1 cancels in BN)
        if (tid < 20) {
            float var1 = 0.0f, m1 = 0.0f;
#pragma unroll
            for (int k = 0; k < 20; ++k) {
                var1 += sP[tid * 20 + k];
                m1    = fmaf(sU[tid * 20 + k], sMu[k], m1);
                m1    = fmaf(sW1[tid * 20 + k], sC0[k], m1);
            }
            float a1 = g1[t * 20 + tid] * rsqrtf(var1 + EPSV);
            sA1[tid] = a1;
            sC1[tid] = fmaf(-m1, a1, be1[t * 20 + tid]);
        }
        __syncthreads();

        // ---- forward layers 1,2 (y2 stays in registers)
        float y2[RPT][HH];
#pragma unroll
        for (int r = 0; r < RPT; ++r) {
            float hn[20];
#pragma unroll
            for (int k = 0; k < 10; ++k) hn[k]      = fmaf(xv[r][k], sA0[k],      sC0[k]);
#pragma unroll
            for (int k = 0; k < 10; ++k) hn[10 + k] = fmaf(pv[r][k], sA0[10 + k], sC0[10 + k]);

            float h1[20];
#pragma unroll
            for (int j = 0; j < 20; ++j) {
                float y = 0.0f;
#pragma unroll
                for (int k = 0; k < 20; ++k) y = fmaf(sW1[j * 20 + k], hn[k], y);
                h1[j] = fmaxf(fmaf(y, sA1[j], sC1[j]), 0.0f);
            }
#pragma unroll
            for (int j = 0; j < 20; ++j) {
                float y = 0.0f;
#pragma unroll
                for (int k = 0; k < 20; ++k) y = fmaf(sW2[j * 20 + k], h1[k], y);
                y2[r][j] = y;   // b2 cancels in BN2
            }
        }

        // ---- statsB (combine rows, then reduce)
#pragma unroll
        for (int j = 0; j < 20; ++j) {
            float r = rowsum16(y2[0][j] + y2[1][j]);
            if (lane15) lred[grp * NVA + j] = r;
        }
#pragma unroll
        for (int j = 0; j < 20; ++j) {
            float r = rowsum16(fmaf(y2[0][j], y2[0][j], y2[1][j] * y2[1][j]));
            if (lane15) lred[grp * NVA + 20 + j] = r;
        }
        __syncthreads();
        if (tid < NVB) {
            float acc = 0.0f;
#pragma unroll
            for (int g = 0; g < 16; ++g) acc += lred[g * NVA + tid];
            atomicAdd(redB + (size_t)t * STRB + tid * NS + slot, acc);
        }

        // ================= barrier 1 (statsB ready) =================
        gbar(ctr + (size_t)(2 * t) * CTRW, tid, grpN);

        // ---- BN2 params (relaxed agent atomic readback)
        if (tid < NVB) {
            const float* p = redB + (size_t)t * STRB + tid * NS;
            float s = 0.0f;
#pragma unroll
            for (int i = 0; i < NS; ++i) s += aloadf(p + i);
            sM[tid] = s;
        }
        __syncthreads();
        if (tid < 20) {
            float m   = sM[tid] * INV_B;
            float var = fmaf(-m, m, sM[20 + tid] * INV_B);
            float a   = g2[t * 20 + tid] * rsqrtf(var + EPSV);
            sA2[tid] = a;
            sC2[tid] = fmaf(-m, a, be2[t * 20 + tid]);
        }
        __syncthreads();

        // ---- layer 3 + output + prev (registers)
        float ov[RPT][DD];
#pragma unroll
        for (int r = 0; r < RPT; ++r) {
            float h2[20];
#pragma unroll
            for (int j = 0; j < 20; ++j)
                h2[j] = fmaxf(fmaf(y2[r][j], sA2[j], sC2[j]), 0.0f);
#pragma unroll
            for (int d = 0; d < DD; ++d) {
                float a = sB3[d];
#pragma unroll
                for (int j = 0; j < 20; ++j)
                    a = fmaf(sW3[d * 20 + j], h2[j], a);
                ov[r][d] = a;
            }
            float2* po = reinterpret_cast<float2*>(outg + (size_t)(gt + r * TT) * TS * DD + t * DD);
#pragma unroll
            for (int i = 0; i < 5; ++i) po[i] = make_float2(ov[r][2 * i], ov[r][2 * i + 1]);
#pragma unroll
            for (int d = 0; d < DD; ++d) pv[r][d] = ov[r][d];
        }

        // ---- statsA(t+1) + barrier 2
        if (t + 1 < TS) {
#define H0A(i) ((i) < DD ? xn[0][i] : ov[0][(i) - DD])
#define H0B(i) ((i) < DD ? xn[1][i] : ov[1][(i) - DD])
            {
                int v = 0;
#pragma unroll
                for (int k = 0; k < 2 * DD; ++k) {
#pragma unroll
                    for (int l = k; l < 2 * DD; ++l) {
                        float p = fmaf(H0A(k), H0A(l), H0B(k) * H0B(l));
                        float r = rowsum16(p);
                        if (lane15) lred[grp * NVA + v] = r;
                        ++v;
                    }
                }
#pragma unroll
                for (int k = 0; k < 2 * DD; ++k) {
                    float r = rowsum16(H0A(k) + H0B(k));
                    if (lane15) lred[grp * NVA + 210 + k] = r;
                }
            }
#undef H0A
#undef H0B
            __syncthreads();
            if (tid < NVA) {
                float acc = 0.0f;
#pragma unroll
                for (int g = 0; g < 16; ++g) acc += lred[g * NVA + tid];
                atomicAdd(redA + (size_t)(t + 1) * STRA + tid * NS + slot, acc);
            }
            gbar(ctr + (size_t)(2 * t + 1) * CTRW, tid, grpN);

#pragma unroll
            for (int r = 0; r < RPT; ++r)
#pragma unroll
                for (int d = 0; d < DD; ++d) xv[r][d] = xn[r][d];
        }
    }
}

extern "C" void kernel_launch(void* const* d_in, const int* in_sizes, int n_in,
                              void* d_out, int out_size, void* d_ws, size_t ws_size,
                              hipStream_t stream) {
    const float* x   = (const float*)d_in[0];
    const float* g0  = (const float*)d_in[1];
    const float* be0 = (const float*)d_in[2];
    const float* W1  = (const float*)d_in[3];
    const float* b1  = (const float*)d_in[4];   (void)b1;  // cancels in BN1
    const float* g1  = (const float*)d_in[5];
    const float* be1 = (const float*)d_in[6];
    const float* W2  = (const float*)d_in[7];
    const float* b2  = (const float*)d_in[8];   (void)b2;  // cancels in BN2
    const float* g2  = (const float*)d_in[9];
    const float* be2 = (const float*)d_in[10];
    const float* W3  = (const float*)d_in[11];
    const float* b3  = (const float*)d_in[12];
    float* out = (float*)d_out;

    const size_t redA_f = (size_t)TS * STRA;    // 55200
    const size_t redB_f = (size_t)TS * STRB;    //  9600
    const size_t ctr_u  = (size_t)NPH * CTRW;   //  9760
    float*    redA  = (float*)d_ws;
    float*    redB  = redA + redA_f;
    unsigned* ctr   = (unsigned*)(redB + redB_f);

    // zero stat accumulators + barrier counters each replay
    hipMemsetAsync(d_ws, 0, (redA_f + redB_f) * 4 + ctr_u * 4, stream);

    rnn_all<<<NBLK, NTHR, 0, stream>>>(x, out, W1, W2, W3, b3,
                                       g0, be0, g1, be1, g2, be2,
                                       redA, redB, ctr);
}